// Round 10
// baseline (136.577 us; speedup 1.0000x reference)
//
#include <hip/hip_runtime.h>

#define F_IN  128
#define H_MID 16
#define C_OUT 8
#define XS_PAD (F_IN + 4)
#define TROWS 32            // gemm1 tile rows (double-buffered)
#define CHUNK 4096          // edges per k_build block
#define NBMAX 512           // bucket array size (NB = ceil(N/256) <= 512)
#define CAP   8192          // fixed per-bucket capacity (bucket mean ~4092, sigma ~64)
#define GEMM_SHF (2 * TROWS * XS_PAD + F_IN * H_MID)   // 10496 floats = 41984 B

// ---- zero bcursor (cheap kernel; avoids fillBuffer in graph) ----
__global__ void __launch_bounds__(512) k_zero512(int* __restrict__ p) {
    p[threadIdx.x] = 0;
}

// ======================================================================
// gemm1 worker (device fn): h1 = x @ W1 (UNSCALED), tiles [t0,t1) with
// stride S, offset j. Double-buffered LDS staging from a 42KB arena.
// Requires 256-thread blocks. dis is applied later in k_agg16f.
// ======================================================================
__device__ __forceinline__ void gemm1_part(
        const float* __restrict__ x, const float* __restrict__ W1,
        float* __restrict__ h1, int N, int t0, int t1, int j, int S,
        float* __restrict__ arena) {
    float* xs  = arena;                          // [2][TROWS*XS_PAD]
    float* W1s = arena + 2 * TROWS * XS_PAD;     // [F_IN*H_MID]
    const int t = threadIdx.x;
    for (int i = t; i < F_IN * H_MID; i += 256) W1s[i] = W1[i];
    const int c  = t & 15;
    const int r0 = t >> 4;
    int tile = t0 + j;
    if (tile >= t1) return;

    float4 st[4];
    auto stage_load = [&](int tl) {
        const float4* xg = reinterpret_cast<const float4*>(x + (long long)tl * TROWS * F_IN);
        const int nfl = ((N - tl * TROWS < TROWS) ? (N - tl * TROWS) : TROWS) * (F_IN / 4);
#pragma unroll
        for (int k = 0; k < 4; ++k) {
            const int i = t + k * 256;
            st[k] = (i < nfl) ? xg[i] : make_float4(0.f, 0.f, 0.f, 0.f);
        }
    };
    auto stage_write = [&](int buf) {
#pragma unroll
        for (int k = 0; k < 4; ++k) {
            const int i = t + k * 256;
            *reinterpret_cast<float4*>(&xs[buf * TROWS * XS_PAD + (i >> 5) * XS_PAD + (i & 31) * 4]) = st[k];
        }
    };

    stage_load(tile);
    stage_write(0);
    __syncthreads();
    int buf = 0;
    while (true) {
        const int next = tile + S;
        if (next < t1) stage_load(next);
        const float* xr0 = &xs[buf * TROWS * XS_PAD + r0 * XS_PAD];
        const float* xr1 = xr0 + 16 * XS_PAD;
        float acc0 = 0.0f, acc1 = 0.0f;
#pragma unroll 4
        for (int k4 = 0; k4 < F_IN / 4; ++k4) {
            const float4 v0 = *reinterpret_cast<const float4*>(&xr0[k4 * 4]);
            const float4 v1 = *reinterpret_cast<const float4*>(&xr1[k4 * 4]);
            const float w0 = W1s[(k4 * 4 + 0) * H_MID + c];
            const float w1 = W1s[(k4 * 4 + 1) * H_MID + c];
            const float w2 = W1s[(k4 * 4 + 2) * H_MID + c];
            const float w3 = W1s[(k4 * 4 + 3) * H_MID + c];
            acc0 = fmaf(v0.x, w0, acc0); acc1 = fmaf(v1.x, w0, acc1);
            acc0 = fmaf(v0.y, w1, acc0); acc1 = fmaf(v1.y, w1, acc1);
            acc0 = fmaf(v0.z, w2, acc0); acc1 = fmaf(v1.z, w2, acc1);
            acc0 = fmaf(v0.w, w3, acc0); acc1 = fmaf(v1.w, w3, acc1);
        }
        const long long row0 = (long long)tile * TROWS + r0;
        const long long row1 = row0 + 16;
        if (row0 < N) h1[row0 * H_MID + c] = acc0;
        if (row1 < N) h1[row1 * H_MID + c] = acc1;
        if (next >= t1) break;
        __syncthreads();
        stage_write(buf ^ 1);
        __syncthreads();
        buf ^= 1;
        tile = next;
    }
}

// ======================================================================
// k_build_g: direct-slot bucket scatter (NO bhist/bscan needed) + gemm1.
// Bucket bk owns bed[bk*CAP .. bk*CAP+CAP); space reserved via bcursor.
// Edge record: int2 { src | (d&255)<<18 , float_bits(ew) }, N <= 131072.
// ======================================================================
__global__ void __launch_bounds__(256) k_build_g(
        const int* __restrict__ src, const int* __restrict__ dst,
        const float* __restrict__ ew, int* __restrict__ bcursor,
        int2* __restrict__ bed, int E, int NB,
        const float* __restrict__ x, const float* __restrict__ W1,
        float* __restrict__ h1, int N, int t0, int t1, int NCSR, int NG) {
    struct S {
        int hist4[4][NBMAX];
        int cur4[4][NBMAX];
        int scn[NBMAX], tot[NBMAX], base[NBMAX];
        int2 sorted[CHUNK];
        unsigned short bof[CHUNK];
    };
    union Shm { S s; float g[GEMM_SHF]; };
    __shared__ Shm u;
    const int b = blockIdx.x;
    if (b >= NCSR) { gemm1_part(x, W1, h1, N, t0, t1, b - NCSR, NG, u.g); return; }

    const int t = threadIdx.x;
    const int w = t >> 6;               // wave id 0..3
    const int c0 = b * CHUNK;
    const int n = (E - c0 < CHUNK) ? (E - c0) : CHUNK;

    for (int l = t; l < NBMAX; l += 256) {
        u.s.hist4[0][l] = 0; u.s.hist4[1][l] = 0; u.s.hist4[2][l] = 0; u.s.hist4[3][l] = 0;
    }
    __syncthreads();
    for (int i = t; i < n; i += 256)
        atomicAdd(&u.s.hist4[w][((unsigned)dst[c0 + i]) >> 8], 1);
    __syncthreads();
    {
        const int l0 = t, l1 = t + 256;
        const int q0 = u.s.hist4[0][l0] + u.s.hist4[1][l0] + u.s.hist4[2][l0] + u.s.hist4[3][l0];
        const int q1 = u.s.hist4[0][l1] + u.s.hist4[1][l1] + u.s.hist4[2][l1] + u.s.hist4[3][l1];
        u.s.tot[l0] = q0; u.s.tot[l1] = q1;
        u.s.scn[l0] = q0; u.s.scn[l1] = q1;
    }
    __syncthreads();
#pragma unroll
    for (int off = 1; off < 512; off <<= 1) {
        const int i1 = t + 256;
        const int v0 = (t >= off) ? u.s.scn[t - off] : 0;
        const int v1 = u.s.scn[i1 - off];
        __syncthreads();
        u.s.scn[t] += v0;
        u.s.scn[i1] += v1;
        __syncthreads();
    }
    for (int l = t; l < NBMAX; l += 256) {
        int e = u.s.scn[l] - u.s.tot[l];
        u.s.cur4[0][l] = e;
        e += u.s.hist4[0][l]; u.s.cur4[1][l] = e;
        e += u.s.hist4[1][l]; u.s.cur4[2][l] = e;
        e += u.s.hist4[2][l]; u.s.cur4[3][l] = e;
    }
    __syncthreads();
    for (int i = t; i < n; i += 256) {
        const int s  = src[c0 + i];
        const int d  = dst[c0 + i];
        const float wt = ew[c0 + i];
        const int bk = ((unsigned)d) >> 8;
        const int slot = atomicAdd(&u.s.cur4[w][bk], 1);
        u.s.sorted[slot] = make_int2(s | ((d & 255) << 18), __float_as_int(wt));
        u.s.bof[slot] = (unsigned short)bk;
    }
    __syncthreads();
    // reserve bucket space directly (fixed-capacity buckets; no bptr)
    for (int l = t; l < NB; l += 256)
        u.s.base[l] = u.s.tot[l] ? (l * CAP + atomicAdd(&bcursor[l], u.s.tot[l])) : 0;
    __syncthreads();
    for (int i = t; i < n; i += 256) {
        const int bk = u.s.bof[i];
        const int excl = u.s.scn[bk] - u.s.tot[bk];
        const int pos = u.s.base[bk] + (i - excl);
        if (pos < (bk + 1) * CAP) bed[pos] = u.s.sorted[i];  // clamp (never hit: 16-sigma headroom)
    }
}

// ======================================================================
// k_bsort_g: per-bucket counting sort -> ed (bucket-strided), rowseg, dis
// ======================================================================
__global__ void __launch_bounds__(256) k_bsort_g(
        const int2* __restrict__ bed, const int* __restrict__ bcursor,
        int2* __restrict__ rowseg, float* __restrict__ dis,
        int2* __restrict__ ed, int N, int NB,
        const float* __restrict__ x, const float* __restrict__ W1,
        float* __restrict__ h1, int t0, int t1, int NCSR, int NG) {
    struct S { int hist[256], scn[256], cur[256]; float degw[256]; };
    union Shm { S s; float g[GEMM_SHF]; };
    __shared__ Shm u;
    const int b = blockIdx.x;
    if (b >= NCSR) { gemm1_part(x, W1, h1, N, t0, t1, b - NCSR, NG, u.g); return; }

    const int t = threadIdx.x;
    const int r0 = b << 8;
    const int L = (N - r0 < 256) ? (N - r0) : 256;
    const int e0 = b * CAP;
    int M = bcursor[b];
    if (M > CAP) M = CAP;

    u.s.hist[t] = 0;
    u.s.degw[t] = 0.0f;
    __syncthreads();
    for (int i = t; i < M; i += 256) {
        const int2 rec = bed[e0 + i];
        const int dl = ((unsigned)rec.x) >> 18;
        atomicAdd(&u.s.hist[dl], 1);
        atomicAdd(&u.s.degw[dl], __int_as_float(rec.y));
    }
    __syncthreads();
    u.s.scn[t] = u.s.hist[t];
    __syncthreads();
#pragma unroll
    for (int off = 1; off < 256; off <<= 1) {
        int v = (t >= off) ? u.s.scn[t - off] : 0;
        __syncthreads();
        u.s.scn[t] += v;
        __syncthreads();
    }
    const int excl = u.s.scn[t] - u.s.hist[t];
    if (t < L) {
        rowseg[r0 + t] = make_int2(e0 + excl, e0 + u.s.scn[t]);
        dis[r0 + t] = rsqrtf(1.0f + u.s.degw[t]);   // self-loop weight 1 => deg >= 1
    }
    u.s.cur[t] = excl;
    __syncthreads();
    for (int i = t; i < M; i += 256) {
        const int2 rec = bed[e0 + i];
        const int dl = ((unsigned)rec.x) >> 18;
        const int slot = atomicAdd(&u.s.cur[dl], 1);
        ed[e0 + slot] = make_int2(rec.x & 0x3FFFF, rec.y);
    }
}

// ======================================================================
// Aggregation kernels (h1 is UNSCALED; dis applied here)
// ======================================================================

// layer-1 agg + fused ReLU + fused gemm2:
//   r_c = relu(b1[c] + dis[d]*(h1[d,c]*dis[d] + sum h1[s,c]*dis[s]*ew))
//   h2s[d,j] = dis[d] * sum_c r_c * W2[c][j]
__global__ void __launch_bounds__(256) k_agg16f(
        const int2* __restrict__ rowseg, const int2* __restrict__ ed,
        const float* __restrict__ h, const float* __restrict__ dis,
        const float* __restrict__ b1, const float* __restrict__ W2,
        float* __restrict__ h2s, int N) {
    __shared__ float W2s[H_MID * C_OUT];
    if (threadIdx.x < H_MID * C_OUT) W2s[threadIdx.x] = W2[threadIdx.x];
    __syncthreads();
    const long long tg = (long long)blockIdx.x * 256 + threadIdx.x;
    const int node = (int)(tg >> 4);
    const int c = (int)(tg & 15);
    if (node >= N) return;
    const int2 seg = rowseg[node];
    const float dn = dis[node];
    float a0 = h[(long long)node * H_MID + c] * dn;   // self loop (weight 1, dis[d])
    float a1 = 0.f, a2 = 0.f, a3 = 0.f;
    int e = seg.x;
    for (; e + 3 < seg.y; e += 4) {
        const int2 p0 = ed[e],     p1 = ed[e + 1];
        const int2 p2 = ed[e + 2], p3 = ed[e + 3];
        const float w0 = __int_as_float(p0.y) * dis[p0.x];
        const float w1 = __int_as_float(p1.y) * dis[p1.x];
        const float w2 = __int_as_float(p2.y) * dis[p2.x];
        const float w3 = __int_as_float(p3.y) * dis[p3.x];
        a0 = fmaf(h[(long long)p0.x * H_MID + c], w0, a0);
        a1 = fmaf(h[(long long)p1.x * H_MID + c], w1, a1);
        a2 = fmaf(h[(long long)p2.x * H_MID + c], w2, a2);
        a3 = fmaf(h[(long long)p3.x * H_MID + c], w3, a3);
    }
    for (; e < seg.y; ++e) {
        const int2 p = ed[e];
        a0 = fmaf(h[(long long)p.x * H_MID + c], __int_as_float(p.y) * dis[p.x], a0);
    }
    float r = fmaf((a0 + a1) + (a2 + a3), dn, b1[c]);
    r = fmaxf(r, 0.0f);                       // fused ReLU
    float h2 = 0.0f;
#pragma unroll
    for (int cc = 0; cc < H_MID; ++cc) {
        const float rc = __shfl(r, cc, 16);
        h2 = fmaf(rc, W2s[cc * C_OUT + (c & 7)], h2);
    }
    if (c < C_OUT) h2s[(long long)node * C_OUT + c] = h2 * dn;
}

// layer-2 agg: out = b2 + dis[d]*(h2s[d] + sum h2s[s]*ew)  (h2s pre-scaled by dis)
__global__ void __launch_bounds__(256) k_agg8(
        const int2* __restrict__ rowseg, const int2* __restrict__ ed,
        const float* __restrict__ h, const float* __restrict__ dis,
        const float* __restrict__ b2, float* __restrict__ out, int N) {
    const long long tg = (long long)blockIdx.x * 256 + threadIdx.x;
    const int node = (int)(tg >> 3);
    const int c = (int)(tg & 7);
    if (node >= N) return;
    const int2 seg = rowseg[node];
    float a0 = h[(long long)node * C_OUT + c];
    float a1 = 0.f, a2 = 0.f, a3 = 0.f;
    int e = seg.x;
    for (; e + 3 < seg.y; e += 4) {
        const int2 p0 = ed[e],     p1 = ed[e + 1];
        const int2 p2 = ed[e + 2], p3 = ed[e + 3];
        a0 = fmaf(h[(long long)p0.x * C_OUT + c], __int_as_float(p0.y), a0);
        a1 = fmaf(h[(long long)p1.x * C_OUT + c], __int_as_float(p1.y), a1);
        a2 = fmaf(h[(long long)p2.x * C_OUT + c], __int_as_float(p2.y), a2);
        a3 = fmaf(h[(long long)p3.x * C_OUT + c], __int_as_float(p3.y), a3);
    }
    for (; e < seg.y; ++e) {
        const int2 p = ed[e];
        a0 = fmaf(h[(long long)p.x * C_OUT + c], __int_as_float(p.y), a0);
    }
    out[(long long)node * C_OUT + c] = fmaf((a0 + a1) + (a2 + a3), dis[node], b2[c]);
}

// ======================================================================
// Fallback: atomic pipeline (size-guard escape hatch)
// ======================================================================
__global__ void k_init_deg(float* __restrict__ deg, int N) {
    int i = blockIdx.x * blockDim.x + threadIdx.x;
    if (i < N) deg[i] = 1.0f;
}
__global__ void k_scatter_deg(const int* __restrict__ dst, const float* __restrict__ ew,
                              float* __restrict__ deg, int E) {
    int e = blockIdx.x * blockDim.x + threadIdx.x;
    if (e < E) atomicAdd(&deg[dst[e]], ew[e]);
}
__global__ void k_rsqrt(float* __restrict__ deg, int N) {
    int i = blockIdx.x * blockDim.x + threadIdx.x;
    if (i < N) {
        float v = deg[i];
        deg[i] = (v > 0.0f) ? rsqrtf(v) : 0.0f;
    }
}
__global__ void k_gemm1_r2(const float* __restrict__ x, const float* __restrict__ W1,
                           const float* __restrict__ b1, const float* __restrict__ dis,
                           float* __restrict__ h1, float* __restrict__ a1, int N) {
    __shared__ float W1s[F_IN * H_MID];
    for (int i = threadIdx.x; i < F_IN * H_MID; i += blockDim.x) W1s[i] = W1[i];
    __syncthreads();
    const int c   = threadIdx.x & 15;
    const int lr  = threadIdx.x >> 4;
    const int rpb = blockDim.x >> 4;
    for (long long row = (long long)blockIdx.x * rpb + lr; row < N;
         row += (long long)gridDim.x * rpb) {
        const float4* xr = reinterpret_cast<const float4*>(x + row * F_IN);
        float acc = 0.0f;
#pragma unroll
        for (int k4 = 0; k4 < F_IN / 4; ++k4) {
            float4 v = xr[k4];
            acc = fmaf(v.x, W1s[(k4 * 4 + 0) * H_MID + c], acc);
            acc = fmaf(v.y, W1s[(k4 * 4 + 1) * H_MID + c], acc);
            acc = fmaf(v.z, W1s[(k4 * 4 + 2) * H_MID + c], acc);
            acc = fmaf(v.w, W1s[(k4 * 4 + 3) * H_MID + c], acc);
        }
        h1[row * H_MID + c] = acc;
        float di = dis[row];
        a1[row * H_MID + c] = fmaf(acc, di * di, b1[c]);
    }
}
template <int CH>
__global__ void k_agg_at(const int* __restrict__ src, const int* __restrict__ dst,
                         const float* __restrict__ ew, const float* __restrict__ dis,
                         const float* __restrict__ h, float* __restrict__ out, long long E) {
    const int LOG = (CH == 16) ? 4 : 3;
    const long long total  = E << LOG;
    const long long stride = (long long)gridDim.x * blockDim.x;
    for (long long idx = (long long)blockIdx.x * blockDim.x + threadIdx.x; idx < total;
         idx += stride) {
        const long long e = idx >> LOG;
        const int c = (int)(idx & (CH - 1));
        const int s = src[e];
        const int d = dst[e];
        const float norm = dis[s] * ew[e] * dis[d];
        atomicAdd(out + (long long)d * CH + c, h[(long long)s * CH + c] * norm);
    }
}
__global__ void k_gemm2_r2(const float* __restrict__ a1, const float* __restrict__ W2,
                           const float* __restrict__ b2, const float* __restrict__ dis,
                           float* __restrict__ h2, float* __restrict__ out, int N) {
    __shared__ float W2s[H_MID * C_OUT];
    if (threadIdx.x < H_MID * C_OUT) W2s[threadIdx.x] = W2[threadIdx.x];
    __syncthreads();
    const int c   = threadIdx.x & 7;
    const int lr  = threadIdx.x >> 3;
    const int rpb = blockDim.x >> 3;
    for (long long row = (long long)blockIdx.x * rpb + lr; row < N;
         row += (long long)gridDim.x * rpb) {
        const float4* ar = reinterpret_cast<const float4*>(a1 + row * H_MID);
        float acc = 0.0f;
#pragma unroll
        for (int k4 = 0; k4 < H_MID / 4; ++k4) {
            float4 v = ar[k4];
            acc = fmaf(fmaxf(v.x, 0.0f), W2s[(k4 * 4 + 0) * C_OUT + c], acc);
            acc = fmaf(fmaxf(v.y, 0.0f), W2s[(k4 * 4 + 1) * C_OUT + c], acc);
            acc = fmaf(fmaxf(v.z, 0.0f), W2s[(k4 * 4 + 2) * C_OUT + c], acc);
            acc = fmaf(fmaxf(v.w, 0.0f), W2s[(k4 * 4 + 3) * C_OUT + c], acc);
        }
        h2[row * C_OUT + c] = acc;
        float di = dis[row];
        out[row * C_OUT + c] = fmaf(acc, di * di, b2[c]);
    }
}

extern "C" void kernel_launch(void* const* d_in, const int* in_sizes, int n_in,
                              void* d_out, int out_size, void* d_ws, size_t ws_size,
                              hipStream_t stream) {
    const float* x  = (const float*)d_in[0];
    const int*   ei = (const int*)d_in[1];
    const float* ew = (const float*)d_in[2];
    const float* W1 = (const float*)d_in[3];
    const float* b1 = (const float*)d_in[4];
    const float* W2 = (const float*)d_in[5];
    const float* b2 = (const float*)d_in[6];
    float* out = (float*)d_out;

    const int H   = in_sizes[4];            // 16
    const int Fin = in_sizes[3] / H;        // 128
    const int N   = in_sizes[0] / Fin;      // 100000
    const int E   = in_sizes[2];            // 1600000
    const int* src = ei;
    const int* dst = ei + E;
    (void)n_in; (void)out_size;

    char* ws = (char*)d_ws;
    size_t off = 0;
    auto alloc = [&](size_t bytes) {
        void* p = ws + off;
        off = (off + bytes + 255) & ~(size_t)255;
        return p;
    };
    float* dis    = (float*)alloc((size_t)N * sizeof(float));
    float* h1     = (float*)alloc((size_t)N * H_MID * sizeof(float));
    int2*  rowseg = (int2*)alloc((size_t)N * sizeof(int2));
    int*   bcursor= (int*)alloc(NBMAX * sizeof(int));
    const int NB  = (N + 255) >> 8;
    int2*  bed    = (int2*)alloc((size_t)NB * CAP * sizeof(int2));
    int2*  ed     = (int2*)alloc((size_t)NB * CAP * sizeof(int2));
    // h2s aliases bed (dead after k_bsort_g)
    float* h2s = (float*)bed;
    const size_t needed = off;

    const int B = 256;
    const int NCH = (E + CHUNK - 1) / CHUNK;
    const bool fast_ok = (needed <= ws_size) && (N <= 131072) && (NB <= NBMAX) &&
                         (2 * ((E + NB - 1) / NB) <= CAP) &&
                         ((size_t)NB * CAP * sizeof(int2) >= (size_t)N * C_OUT * sizeof(float));

    if (fast_ok) {
        // gemm1 tile split across the two CSR kernels (65/35)
        const int ntiles = (N + TROWS - 1) / TROWS;
        const int tA = (int)((long long)ntiles * 65 / 100);
        const int GB_S = 200, GB_B = 150;

        k_zero512<<<1, 512, 0, stream>>>(bcursor);
        k_build_g<<<NCH + GB_S, B, 0, stream>>>(src, dst, ew, bcursor, bed, E, NB,
                                                x, W1, h1, N, 0, tA, NCH, GB_S);
        k_bsort_g<<<NB + GB_B, B, 0, stream>>>(bed, bcursor, rowseg, dis, ed, N, NB,
                                               x, W1, h1, tA, ntiles, NB, GB_B);
        // layer 1 (+ fused ReLU + fused gemm2)
        k_agg16f<<<(int)(((long long)N * H_MID + B - 1) / B), B, 0, stream>>>(
            rowseg, ed, h1, dis, b1, W2, h2s, N);
        // layer 2
        k_agg8<<<(int)(((long long)N * C_OUT + B - 1) / B), B, 0, stream>>>(
            rowseg, ed, h2s, dis, b2, out, N);
    } else {
        // fallback: atomic path (~17 MB)
        off = 0;
        float* disF = (float*)alloc((size_t)N * sizeof(float));
        float* h1F  = (float*)alloc((size_t)N * H_MID * sizeof(float));
        float* a1F  = (float*)alloc((size_t)N * H_MID * sizeof(float));
        float* h2   = (float*)alloc((size_t)N * C_OUT * sizeof(float));
        k_init_deg<<<(N + B - 1) / B, B, 0, stream>>>(disF, N);
        k_scatter_deg<<<(E + B - 1) / B, B, 0, stream>>>(dst, ew, disF, E);
        k_rsqrt<<<(N + B - 1) / B, B, 0, stream>>>(disF, N);
        k_gemm1_r2<<<(N + 15) / 16, B, 0, stream>>>(x, W1, b1, disF, h1F, a1F, N);
        k_agg_at<H_MID><<<8192, B, 0, stream>>>(src, dst, ew, disF, h1F, a1F, E);
        k_gemm2_r2<<<(N + 31) / 32, B, 0, stream>>>(a1F, W2, b2, disF, h2, out, N);
        k_agg_at<C_OUT><<<8192, B, 0, stream>>>(src, dst, ew, disF, h2, out, E);
    }
}

// Round 11
// 111.336 us; speedup vs baseline: 1.2267x; 1.2267x over previous
//
#include <hip/hip_runtime.h>

#define F_IN  128
#define H_MID 16
#define C_OUT 8
#define XS_PAD (F_IN + 4)
#define TROWS 32            // gemm1 tile rows (double-buffered)
#define CHUNK 4096          // edges per k_build block
#define NBMAX 512           // bucket array size (NB = ceil(N/256) <= 512)
#define CAP   8192          // fixed per-bucket capacity (bucket mean ~4092, sigma ~64)
#define GEMM_SHF (2 * TROWS * XS_PAD + F_IN * H_MID)   // 10496 floats = 41984 B

// ---- zero bcursor (cheap kernel; avoids fillBuffer in graph) ----
__global__ void __launch_bounds__(512) k_zero512(int* __restrict__ p) {
    p[threadIdx.x] = 0;
}

// ======================================================================
// gemm1 worker (device fn): h1 = x @ W1 (UNSCALED), tiles [t0,t1) with
// stride S, offset j. Double-buffered LDS staging from a 42KB arena.
// Requires 256-thread blocks. dis is applied later in k_agg16f.
// ======================================================================
__device__ __forceinline__ void gemm1_part(
        const float* __restrict__ x, const float* __restrict__ W1,
        float* __restrict__ h1, int N, int t0, int t1, int j, int S,
        float* __restrict__ arena) {
    float* xs  = arena;                          // [2][TROWS*XS_PAD]
    float* W1s = arena + 2 * TROWS * XS_PAD;     // [F_IN*H_MID]
    const int t = threadIdx.x;
    for (int i = t; i < F_IN * H_MID; i += 256) W1s[i] = W1[i];
    const int c  = t & 15;
    const int r0 = t >> 4;
    int tile = t0 + j;
    if (tile >= t1) return;

    float4 st[4];
    auto stage_load = [&](int tl) {
        const float4* xg = reinterpret_cast<const float4*>(x + (long long)tl * TROWS * F_IN);
        const int nfl = ((N - tl * TROWS < TROWS) ? (N - tl * TROWS) : TROWS) * (F_IN / 4);
#pragma unroll
        for (int k = 0; k < 4; ++k) {
            const int i = t + k * 256;
            st[k] = (i < nfl) ? xg[i] : make_float4(0.f, 0.f, 0.f, 0.f);
        }
    };
    auto stage_write = [&](int buf) {
#pragma unroll
        for (int k = 0; k < 4; ++k) {
            const int i = t + k * 256;
            *reinterpret_cast<float4*>(&xs[buf * TROWS * XS_PAD + (i >> 5) * XS_PAD + (i & 31) * 4]) = st[k];
        }
    };

    stage_load(tile);
    stage_write(0);
    __syncthreads();
    int buf = 0;
    while (true) {
        const int next = tile + S;
        if (next < t1) stage_load(next);
        const float* xr0 = &xs[buf * TROWS * XS_PAD + r0 * XS_PAD];
        const float* xr1 = xr0 + 16 * XS_PAD;
        float acc0 = 0.0f, acc1 = 0.0f;
#pragma unroll 4
        for (int k4 = 0; k4 < F_IN / 4; ++k4) {
            const float4 v0 = *reinterpret_cast<const float4*>(&xr0[k4 * 4]);
            const float4 v1 = *reinterpret_cast<const float4*>(&xr1[k4 * 4]);
            const float w0 = W1s[(k4 * 4 + 0) * H_MID + c];
            const float w1 = W1s[(k4 * 4 + 1) * H_MID + c];
            const float w2 = W1s[(k4 * 4 + 2) * H_MID + c];
            const float w3 = W1s[(k4 * 4 + 3) * H_MID + c];
            acc0 = fmaf(v0.x, w0, acc0); acc1 = fmaf(v1.x, w0, acc1);
            acc0 = fmaf(v0.y, w1, acc0); acc1 = fmaf(v1.y, w1, acc1);
            acc0 = fmaf(v0.z, w2, acc0); acc1 = fmaf(v1.z, w2, acc1);
            acc0 = fmaf(v0.w, w3, acc0); acc1 = fmaf(v1.w, w3, acc1);
        }
        const long long row0 = (long long)tile * TROWS + r0;
        const long long row1 = row0 + 16;
        if (row0 < N) h1[row0 * H_MID + c] = acc0;
        if (row1 < N) h1[row1 * H_MID + c] = acc1;
        if (next >= t1) break;
        __syncthreads();
        stage_write(buf ^ 1);
        __syncthreads();
        buf ^= 1;
        tile = next;
    }
}

// ======================================================================
// k_build_g: direct-slot bucket scatter + gemm1 piggyback.
// SINGLE block-level hist/cur (48KB LDS -> 3 blocks/CU; per-wave split
// cost a block/CU for negligible atomic-throughput gain).
// Bucket bk owns bed[bk*CAP ...); space reserved via bcursor.
// Edge record: int2 { src | (d&255)<<18 , float_bits(ew) }, N <= 131072.
// ======================================================================
__global__ void __launch_bounds__(256) k_build_g(
        const int* __restrict__ src, const int* __restrict__ dst,
        const float* __restrict__ ew, int* __restrict__ bcursor,
        int2* __restrict__ bed, int E, int NB,
        const float* __restrict__ x, const float* __restrict__ W1,
        float* __restrict__ h1, int N, int t0, int t1, int NCSR, int NG) {
    struct S {
        int hist[NBMAX], scn[NBMAX], cur[NBMAX], base[NBMAX];
        int2 sorted[CHUNK];
        unsigned short bof[CHUNK];
    };
    union Shm { S s; float g[GEMM_SHF]; };
    __shared__ Shm u;
    const int b = blockIdx.x;
    if (b >= NCSR) { gemm1_part(x, W1, h1, N, t0, t1, b - NCSR, NG, u.g); return; }

    const int t = threadIdx.x;
    const int c0 = b * CHUNK;
    const int n = (E - c0 < CHUNK) ? (E - c0) : CHUNK;

    for (int l = t; l < NBMAX; l += 256) u.s.hist[l] = 0;
    __syncthreads();
    for (int i = t; i < n; i += 256)
        atomicAdd(&u.s.hist[((unsigned)dst[c0 + i]) >> 8], 1);
    __syncthreads();
    u.s.scn[t] = u.s.hist[t];
    u.s.scn[t + 256] = u.s.hist[t + 256];
    __syncthreads();
#pragma unroll
    for (int off = 1; off < 512; off <<= 1) {
        const int i1 = t + 256;
        const int v0 = (t >= off) ? u.s.scn[t - off] : 0;
        const int v1 = u.s.scn[i1 - off];
        __syncthreads();
        u.s.scn[t] += v0;
        u.s.scn[i1] += v1;
        __syncthreads();
    }
    u.s.cur[t] = u.s.scn[t] - u.s.hist[t];
    u.s.cur[t + 256] = u.s.scn[t + 256] - u.s.hist[t + 256];
    __syncthreads();
    for (int i = t; i < n; i += 256) {
        const int s  = src[c0 + i];
        const int d  = dst[c0 + i];
        const float wt = ew[c0 + i];
        const int bk = ((unsigned)d) >> 8;
        const int slot = atomicAdd(&u.s.cur[bk], 1);
        u.s.sorted[slot] = make_int2(s | ((d & 255) << 18), __float_as_int(wt));
        u.s.bof[slot] = (unsigned short)bk;
    }
    __syncthreads();
    // reserve bucket space directly (fixed-capacity buckets)
    for (int l = t; l < NB; l += 256)
        u.s.base[l] = u.s.hist[l] ? (l * CAP + atomicAdd(&bcursor[l], u.s.hist[l])) : 0;
    __syncthreads();
    for (int i = t; i < n; i += 256) {
        const int bk = u.s.bof[i];
        const int excl = u.s.scn[bk] - u.s.hist[bk];
        const int pos = u.s.base[bk] + (i - excl);
        if (pos < (bk + 1) * CAP) bed[pos] = u.s.sorted[i];  // clamp (never hit: 16-sigma headroom)
    }
}

// ======================================================================
// k_bsort_g: per-bucket counting sort -> ed (bucket-strided), rowseg, dis
// ======================================================================
__global__ void __launch_bounds__(256) k_bsort_g(
        const int2* __restrict__ bed, const int* __restrict__ bcursor,
        int2* __restrict__ rowseg, float* __restrict__ dis,
        int2* __restrict__ ed, int N, int NB,
        const float* __restrict__ x, const float* __restrict__ W1,
        float* __restrict__ h1, int t0, int t1, int NCSR, int NG) {
    struct S { int hist[256], scn[256], cur[256]; float degw[256]; };
    union Shm { S s; float g[GEMM_SHF]; };
    __shared__ Shm u;
    const int b = blockIdx.x;
    if (b >= NCSR) { gemm1_part(x, W1, h1, N, t0, t1, b - NCSR, NG, u.g); return; }

    const int t = threadIdx.x;
    const int r0 = b << 8;
    const int L = (N - r0 < 256) ? (N - r0) : 256;
    const int e0 = b * CAP;
    int M = bcursor[b];
    if (M > CAP) M = CAP;

    u.s.hist[t] = 0;
    u.s.degw[t] = 0.0f;
    __syncthreads();
    for (int i = t; i < M; i += 256) {
        const int2 rec = bed[e0 + i];
        const int dl = ((unsigned)rec.x) >> 18;
        atomicAdd(&u.s.hist[dl], 1);
        atomicAdd(&u.s.degw[dl], __int_as_float(rec.y));
    }
    __syncthreads();
    u.s.scn[t] = u.s.hist[t];
    __syncthreads();
#pragma unroll
    for (int off = 1; off < 256; off <<= 1) {
        int v = (t >= off) ? u.s.scn[t - off] : 0;
        __syncthreads();
        u.s.scn[t] += v;
        __syncthreads();
    }
    const int excl = u.s.scn[t] - u.s.hist[t];
    if (t < L) {
        rowseg[r0 + t] = make_int2(e0 + excl, e0 + u.s.scn[t]);
        dis[r0 + t] = rsqrtf(1.0f + u.s.degw[t]);   // self-loop weight 1 => deg >= 1
    }
    u.s.cur[t] = excl;
    __syncthreads();
    for (int i = t; i < M; i += 256) {
        const int2 rec = bed[e0 + i];
        const int dl = ((unsigned)rec.x) >> 18;
        const int slot = atomicAdd(&u.s.cur[dl], 1);
        ed[e0 + slot] = make_int2(rec.x & 0x3FFFF, rec.y);
    }
}

// ======================================================================
// Aggregation kernels (h1 is UNSCALED; dis applied here)
// ======================================================================

// layer-1 agg + fused ReLU + fused gemm2:
//   r_c = relu(b1[c] + dis[d]*(h1[d,c]*dis[d] + sum h1[s,c]*dis[s]*ew))
//   h2s[d,j] = dis[d] * sum_c r_c * W2[c][j]
__global__ void __launch_bounds__(256) k_agg16f(
        const int2* __restrict__ rowseg, const int2* __restrict__ ed,
        const float* __restrict__ h, const float* __restrict__ dis,
        const float* __restrict__ b1, const float* __restrict__ W2,
        float* __restrict__ h2s, int N) {
    __shared__ float W2s[H_MID * C_OUT];
    if (threadIdx.x < H_MID * C_OUT) W2s[threadIdx.x] = W2[threadIdx.x];
    __syncthreads();
    const long long tg = (long long)blockIdx.x * 256 + threadIdx.x;
    const int node = (int)(tg >> 4);
    const int c = (int)(tg & 15);
    if (node >= N) return;
    const int2 seg = rowseg[node];
    const float dn = dis[node];
    float a0 = h[(long long)node * H_MID + c] * dn;   // self loop (weight 1, dis[d])
    float a1 = 0.f, a2 = 0.f, a3 = 0.f;
    int e = seg.x;
    for (; e + 3 < seg.y; e += 4) {
        const int2 p0 = ed[e],     p1 = ed[e + 1];
        const int2 p2 = ed[e + 2], p3 = ed[e + 3];
        const float w0 = __int_as_float(p0.y) * dis[p0.x];
        const float w1 = __int_as_float(p1.y) * dis[p1.x];
        const float w2 = __int_as_float(p2.y) * dis[p2.x];
        const float w3 = __int_as_float(p3.y) * dis[p3.x];
        a0 = fmaf(h[(long long)p0.x * H_MID + c], w0, a0);
        a1 = fmaf(h[(long long)p1.x * H_MID + c], w1, a1);
        a2 = fmaf(h[(long long)p2.x * H_MID + c], w2, a2);
        a3 = fmaf(h[(long long)p3.x * H_MID + c], w3, a3);
    }
    for (; e < seg.y; ++e) {
        const int2 p = ed[e];
        a0 = fmaf(h[(long long)p.x * H_MID + c], __int_as_float(p.y) * dis[p.x], a0);
    }
    float r = fmaf((a0 + a1) + (a2 + a3), dn, b1[c]);
    r = fmaxf(r, 0.0f);                       // fused ReLU
    float h2 = 0.0f;
#pragma unroll
    for (int cc = 0; cc < H_MID; ++cc) {
        const float rc = __shfl(r, cc, 16);
        h2 = fmaf(rc, W2s[cc * C_OUT + (c & 7)], h2);
    }
    if (c < C_OUT) h2s[(long long)node * C_OUT + c] = h2 * dn;
}

// layer-2 agg: out = b2 + dis[d]*(h2s[d] + sum h2s[s]*ew)  (h2s pre-scaled by dis)
__global__ void __launch_bounds__(256) k_agg8(
        const int2* __restrict__ rowseg, const int2* __restrict__ ed,
        const float* __restrict__ h, const float* __restrict__ dis,
        const float* __restrict__ b2, float* __restrict__ out, int N) {
    const long long tg = (long long)blockIdx.x * 256 + threadIdx.x;
    const int node = (int)(tg >> 3);
    const int c = (int)(tg & 7);
    if (node >= N) return;
    const int2 seg = rowseg[node];
    float a0 = h[(long long)node * C_OUT + c];
    float a1 = 0.f, a2 = 0.f, a3 = 0.f;
    int e = seg.x;
    for (; e + 3 < seg.y; e += 4) {
        const int2 p0 = ed[e],     p1 = ed[e + 1];
        const int2 p2 = ed[e + 2], p3 = ed[e + 3];
        a0 = fmaf(h[(long long)p0.x * C_OUT + c], __int_as_float(p0.y), a0);
        a1 = fmaf(h[(long long)p1.x * C_OUT + c], __int_as_float(p1.y), a1);
        a2 = fmaf(h[(long long)p2.x * C_OUT + c], __int_as_float(p2.y), a2);
        a3 = fmaf(h[(long long)p3.x * C_OUT + c], __int_as_float(p3.y), a3);
    }
    for (; e < seg.y; ++e) {
        const int2 p = ed[e];
        a0 = fmaf(h[(long long)p.x * C_OUT + c], __int_as_float(p.y), a0);
    }
    out[(long long)node * C_OUT + c] = fmaf((a0 + a1) + (a2 + a3), dis[node], b2[c]);
}

// ======================================================================
// Fallback: atomic pipeline (size-guard escape hatch)
// ======================================================================
__global__ void k_init_deg(float* __restrict__ deg, int N) {
    int i = blockIdx.x * blockDim.x + threadIdx.x;
    if (i < N) deg[i] = 1.0f;
}
__global__ void k_scatter_deg(const int* __restrict__ dst, const float* __restrict__ ew,
                              float* __restrict__ deg, int E) {
    int e = blockIdx.x * blockDim.x + threadIdx.x;
    if (e < E) atomicAdd(&deg[dst[e]], ew[e]);
}
__global__ void k_rsqrt(float* __restrict__ deg, int N) {
    int i = blockIdx.x * blockDim.x + threadIdx.x;
    if (i < N) {
        float v = deg[i];
        deg[i] = (v > 0.0f) ? rsqrtf(v) : 0.0f;
    }
}
__global__ void k_gemm1_r2(const float* __restrict__ x, const float* __restrict__ W1,
                           const float* __restrict__ b1, const float* __restrict__ dis,
                           float* __restrict__ h1, float* __restrict__ a1, int N) {
    __shared__ float W1s[F_IN * H_MID];
    for (int i = threadIdx.x; i < F_IN * H_MID; i += blockDim.x) W1s[i] = W1[i];
    __syncthreads();
    const int c   = threadIdx.x & 15;
    const int lr  = threadIdx.x >> 4;
    const int rpb = blockDim.x >> 4;
    for (long long row = (long long)blockIdx.x * rpb + lr; row < N;
         row += (long long)gridDim.x * rpb) {
        const float4* xr = reinterpret_cast<const float4*>(x + row * F_IN);
        float acc = 0.0f;
#pragma unroll
        for (int k4 = 0; k4 < F_IN / 4; ++k4) {
            float4 v = xr[k4];
            acc = fmaf(v.x, W1s[(k4 * 4 + 0) * H_MID + c], acc);
            acc = fmaf(v.y, W1s[(k4 * 4 + 1) * H_MID + c], acc);
            acc = fmaf(v.z, W1s[(k4 * 4 + 2) * H_MID + c], acc);
            acc = fmaf(v.w, W1s[(k4 * 4 + 3) * H_MID + c], acc);
        }
        h1[row * H_MID + c] = acc;
        float di = dis[row];
        a1[row * H_MID + c] = fmaf(acc, di * di, b1[c]);
    }
}
template <int CH>
__global__ void k_agg_at(const int* __restrict__ src, const int* __restrict__ dst,
                         const float* __restrict__ ew, const float* __restrict__ dis,
                         const float* __restrict__ h, float* __restrict__ out, long long E) {
    const int LOG = (CH == 16) ? 4 : 3;
    const long long total  = E << LOG;
    const long long stride = (long long)gridDim.x * blockDim.x;
    for (long long idx = (long long)blockIdx.x * blockDim.x + threadIdx.x; idx < total;
         idx += stride) {
        const long long e = idx >> LOG;
        const int c = (int)(idx & (CH - 1));
        const int s = src[e];
        const int d = dst[e];
        const float norm = dis[s] * ew[e] * dis[d];
        atomicAdd(out + (long long)d * CH + c, h[(long long)s * CH + c] * norm);
    }
}
__global__ void k_gemm2_r2(const float* __restrict__ a1, const float* __restrict__ W2,
                           const float* __restrict__ b2, const float* __restrict__ dis,
                           float* __restrict__ h2, float* __restrict__ out, int N) {
    __shared__ float W2s[H_MID * C_OUT];
    if (threadIdx.x < H_MID * C_OUT) W2s[threadIdx.x] = W2[threadIdx.x];
    __syncthreads();
    const int c   = threadIdx.x & 7;
    const int lr  = threadIdx.x >> 3;
    const int rpb = blockDim.x >> 3;
    for (long long row = (long long)blockIdx.x * rpb + lr; row < N;
         row += (long long)gridDim.x * rpb) {
        const float4* ar = reinterpret_cast<const float4*>(a1 + row * H_MID);
        float acc = 0.0f;
#pragma unroll
        for (int k4 = 0; k4 < H_MID / 4; ++k4) {
            float4 v = ar[k4];
            acc = fmaf(fmaxf(v.x, 0.0f), W2s[(k4 * 4 + 0) * C_OUT + c], acc);
            acc = fmaf(fmaxf(v.y, 0.0f), W2s[(k4 * 4 + 1) * C_OUT + c], acc);
            acc = fmaf(fmaxf(v.z, 0.0f), W2s[(k4 * 4 + 2) * C_OUT + c], acc);
            acc = fmaf(fmaxf(v.w, 0.0f), W2s[(k4 * 4 + 3) * C_OUT + c], acc);
        }
        h2[row * C_OUT + c] = acc;
        float di = dis[row];
        out[row * C_OUT + c] = fmaf(acc, di * di, b2[c]);
    }
}

extern "C" void kernel_launch(void* const* d_in, const int* in_sizes, int n_in,
                              void* d_out, int out_size, void* d_ws, size_t ws_size,
                              hipStream_t stream) {
    const float* x  = (const float*)d_in[0];
    const int*   ei = (const int*)d_in[1];
    const float* ew = (const float*)d_in[2];
    const float* W1 = (const float*)d_in[3];
    const float* b1 = (const float*)d_in[4];
    const float* W2 = (const float*)d_in[5];
    const float* b2 = (const float*)d_in[6];
    float* out = (float*)d_out;

    const int H   = in_sizes[4];            // 16
    const int Fin = in_sizes[3] / H;        // 128
    const int N   = in_sizes[0] / Fin;      // 100000
    const int E   = in_sizes[2];            // 1600000
    const int* src = ei;
    const int* dst = ei + E;
    (void)n_in; (void)out_size;

    char* ws = (char*)d_ws;
    size_t off = 0;
    auto alloc = [&](size_t bytes) {
        void* p = ws + off;
        off = (off + bytes + 255) & ~(size_t)255;
        return p;
    };
    float* dis    = (float*)alloc((size_t)N * sizeof(float));
    float* h1     = (float*)alloc((size_t)N * H_MID * sizeof(float));
    int2*  rowseg = (int2*)alloc((size_t)N * sizeof(int2));
    int*   bcursor= (int*)alloc(NBMAX * sizeof(int));
    const int NB  = (N + 255) >> 8;
    int2*  bed    = (int2*)alloc((size_t)NB * CAP * sizeof(int2));
    int2*  ed     = (int2*)alloc((size_t)NB * CAP * sizeof(int2));
    // h2s aliases bed (dead after k_bsort_g)
    float* h2s = (float*)bed;
    const size_t needed = off;

    const int B = 256;
    const int NCH = (E + CHUNK - 1) / CHUNK;
    const bool fast_ok = (needed <= ws_size) && (N <= 131072) && (NB <= NBMAX) &&
                         (2 * ((E + NB - 1) / NB) <= CAP) &&
                         ((size_t)NB * CAP * sizeof(int2) >= (size_t)N * C_OUT * sizeof(float));

    if (fast_ok) {
        // 3 blocks/CU x 256 CUs = 768 resident blocks/dispatch: fill exactly.
        const int ntiles = (N + TROWS - 1) / TROWS;
        const int GB_S = (NCH < 704) ? (768 - NCH) : 64;
        const int GB_B = (NB  < 704) ? (768 - NB)  : 64;
        // gemm tile split 60/40 between the two piggyback hosts
        const int tA = (int)((long long)ntiles * 60 / 100);

        k_zero512<<<1, 512, 0, stream>>>(bcursor);
        k_build_g<<<NCH + GB_S, B, 0, stream>>>(src, dst, ew, bcursor, bed, E, NB,
                                                x, W1, h1, N, 0, tA, NCH, GB_S);
        k_bsort_g<<<NB + GB_B, B, 0, stream>>>(bed, bcursor, rowseg, dis, ed, N, NB,
                                               x, W1, h1, tA, ntiles, NB, GB_B);
        // layer 1 (+ fused ReLU + fused gemm2)
        k_agg16f<<<(int)(((long long)N * H_MID + B - 1) / B), B, 0, stream>>>(
            rowseg, ed, h1, dis, b1, W2, h2s, N);
        // layer 2
        k_agg8<<<(int)(((long long)N * C_OUT + B - 1) / B), B, 0, stream>>>(
            rowseg, ed, h2s, dis, b2, out, N);
    } else {
        // fallback: atomic path (~17 MB)
        off = 0;
        float* disF = (float*)alloc((size_t)N * sizeof(float));
        float* h1F  = (float*)alloc((size_t)N * H_MID * sizeof(float));
        float* a1F  = (float*)alloc((size_t)N * H_MID * sizeof(float));
        float* h2   = (float*)alloc((size_t)N * C_OUT * sizeof(float));
        k_init_deg<<<(N + B - 1) / B, B, 0, stream>>>(disF, N);
        k_scatter_deg<<<(E + B - 1) / B, B, 0, stream>>>(dst, ew, disF, E);
        k_rsqrt<<<(N + B - 1) / B, B, 0, stream>>>(disF, N);
        k_gemm1_r2<<<(N + 15) / 16, B, 0, stream>>>(x, W1, b1, disF, h1F, a1F, N);
        k_agg_at<H_MID><<<8192, B, 0, stream>>>(src, dst, ew, disF, h1F, a1F, E);
        k_gemm2_r2<<<(N + 31) / 32, B, 0, stream>>>(a1F, W2, b2, disF, h2, out, N);
        k_agg_at<C_OUT><<<8192, B, 0, stream>>>(src, dst, ew, disF, h2, out, E);
    }
}